// Round 8
// baseline (1534.727 us; speedup 1.0000x reference)
//
#include <hip/hip_runtime.h>
#include <hip/hip_bf16.h>

// Problem constants (fixed by the reference)
constexpr int kN   = 50000;
constexpr int kE   = 800000;
constexpr int kIN  = 64;
constexpr int kMC  = 16;
constexpr int kH   = 4;
constexpr int kC   = 16;
constexpr int kHID = 128;
constexpr float kNEG = 0.2f;
constexpr float kEPS = 1e-5f;

__device__ __forceinline__ float lrelu(float x) { return x > 0.f ? x : kNEG * x; }

// ---------------- graph build ----------------

__global__ void k_count(const int* __restrict__ ei, int* __restrict__ cnt) {
    int e = blockIdx.x * blockDim.x + threadIdx.x;
    if (e < kE) atomicAdd(&cnt[ei[kE + e]], 1);   // dst = ei[1][e]
}

// single block, 1024 threads: exclusive scan of cnt -> rp, also dinv = rsqrt(cnt+1)
__global__ void k_scan(const int* __restrict__ cnt, int* __restrict__ rp,
                       float* __restrict__ dinv) {
    __shared__ int wsum[16];
    __shared__ int chunk_base;
    int tid = threadIdx.x, lane = tid & 63, wid = tid >> 6;
    if (tid == 0) chunk_base = 0;
    __syncthreads();
    for (int base = 0; base < kN; base += 1024) {
        int i = base + tid;
        int v = (i < kN) ? cnt[i] : 0;
        if (i < kN) dinv[i] = rsqrtf((float)(v + 1));
        // wave inclusive scan
        int s = v;
        #pragma unroll
        for (int off = 1; off < 64; off <<= 1) {
            int t = __shfl_up(s, off);
            if (lane >= off) s += t;
        }
        if (lane == 63) wsum[wid] = s;
        __syncthreads();
        if (wid == 0) {
            int t = (lane < 16) ? wsum[lane] : 0;
            #pragma unroll
            for (int off = 1; off < 16; off <<= 1) {
                int u = __shfl_up(t, off);
                if (lane >= off) t += u;
            }
            if (lane < 16) wsum[lane] = t;
        }
        __syncthreads();
        int wbase = (wid > 0) ? wsum[wid - 1] : 0;
        int total = wsum[15];
        int excl = chunk_base + wbase + s - v;
        if (i < kN) rp[i] = excl;
        __syncthreads();
        if (tid == 0) chunk_base += total;
        __syncthreads();
    }
    if (threadIdx.x == 0) rp[kN] = chunk_base;
}

__global__ void k_fill(const int* __restrict__ ei, const int* __restrict__ rp,
                       int* __restrict__ fill, int* __restrict__ col) {
    int e = blockIdx.x * blockDim.x + threadIdx.x;
    if (e < kE) {
        int d = ei[kE + e];
        int pos = rp[d] + atomicAdd(&fill[d], 1);
        col[pos] = ei[e];
    }
}

// ---------------- normalized aggregation (scalar, for F=16): ----
// out[v] = dinv[v]*(dinv[v]*in[v] + sum_u dinv[u]*in[u])

template <int F>
__global__ void k_agg(const float* __restrict__ in, float* __restrict__ out,
                      const float* __restrict__ dinv, const int* __restrict__ rp,
                      const int* __restrict__ col) {
    constexpr int NPB = 256 / F;
    int node = blockIdx.x * NPB + threadIdx.x / F;
    int f = threadIdx.x % F;
    if (node >= kN) return;
    float dv = dinv[node];
    float acc = dv * in[(size_t)node * F + f];     // self loop term (dinv[v]^2 * in[v]) /dv
    int b = rp[node], e2 = rp[node + 1];
    for (int i = b; i < e2; ++i) {
        int u = col[i];
        acc += dinv[u] * in[(size_t)u * F + f];
    }
    out[(size_t)node * F + f] = dv * acc;
}

// ---- vectorized aggregation for F=128: 32 lanes/node, float4 per lane ----

__global__ void k_agg128v(const float* __restrict__ in, float* __restrict__ out,
                          const float* __restrict__ dinv, const int* __restrict__ rp,
                          const int* __restrict__ col) {
    int node = blockIdx.x * 8 + threadIdx.x / 32;   // 8 nodes per 256-thread block
    int f4 = threadIdx.x & 31;                      // float4 index: cols [4*f4, 4*f4+4)
    if (node >= kN) return;
    const float4* in4 = (const float4*)in;
    float dv = dinv[node];
    float4 v = in4[(size_t)node * 32 + f4];
    float4 acc = make_float4(dv * v.x, dv * v.y, dv * v.z, dv * v.w);
    int b = rp[node], e2 = rp[node + 1];
    for (int i = b; i < e2; ++i) {
        int u = col[i];
        float du = dinv[u];
        float4 w = in4[(size_t)u * 32 + f4];
        acc.x += du * w.x; acc.y += du * w.y; acc.z += du * w.z; acc.w += du * w.w;
    }
    ((float4*)out)[(size_t)node * 32 + f4] =
        make_float4(dv * acc.x, dv * acc.y, dv * acc.z, dv * acc.w);
}

// ---------------- mf = relu(am @ w0 + b0), am: N x 16, w0: 16 x 128 ----------------

__global__ void k_mf(const float* __restrict__ am, const float* __restrict__ w0,
                     const float* __restrict__ b0, float* __restrict__ mf) {
    __shared__ float w[16 * 128];
    __shared__ float a[16 * 16];
    int tid = threadIdx.x;
    int n0 = blockIdx.x * 16;
    {   // stage w0: 2048 floats = 512 float4, 2 per thread
        const float4* w04 = (const float4*)w0;
        float4* w4 = (float4*)w;
        #pragma unroll
        for (int i = 0; i < 2; ++i) w4[tid + 256 * i] = w04[tid + 256 * i];
        // stage am tile: 256 floats = 64 float4
        if (tid < 64) {
            const float4* am4 = (const float4*)am;   // row = 4 float4
            int node = n0 + tid / 4;
            ((float4*)a)[tid] = (node < kN) ? am4[(size_t)node * 4 + (tid & 3)]
                                            : make_float4(0.f, 0.f, 0.f, 0.f);
        }
    }
    __syncthreads();
    int f = tid % 128, g = tid / 128;   // g in {0,1}
    float bf = b0[f];
    for (int j = 0; j < 8; ++j) {
        int nl = g * 8 + j;
        int node = n0 + nl;
        if (node < kN) {
            float acc = bf;
            #pragma unroll
            for (int k = 0; k < 16; ++k) acc += a[nl * 16 + k] * w[k * 128 + f];
            mf[(size_t)node * 128 + f] = fmaxf(acc, 0.f);
        }
    }
}

// ---------------- BatchNorm stats (biased var) over N rows of 64 cols ----------------

__global__ void k_bnstats(const float* __restrict__ x, float* __restrict__ stats) {
    int f = threadIdx.x % 64, r0 = threadIdx.x / 64;  // 4 row groups
    float s = 0.f, s2 = 0.f;
    for (int v = blockIdx.x * 4 + r0; v < kN; v += gridDim.x * 4) {
        float val = x[(size_t)v * 64 + f];
        s += val; s2 += val * val;
    }
    __shared__ float sh[256], sh2[256];
    sh[threadIdx.x] = s; sh2[threadIdx.x] = s2;
    __syncthreads();
    if (threadIdx.x < 64) {
        s  = sh[threadIdx.x]  + sh[threadIdx.x + 64]  + sh[threadIdx.x + 128]  + sh[threadIdx.x + 192];
        s2 = sh2[threadIdx.x] + sh2[threadIdx.x + 64] + sh2[threadIdx.x + 128] + sh2[threadIdx.x + 192];
        atomicAdd(&stats[f], s);
        atomicAdd(&stats[64 + f], s2);
    }
}

__global__ void k_bnfin(const float* __restrict__ stats, float* __restrict__ mu_rstd) {
    int f = threadIdx.x;
    if (f < 64) {
        float mu = stats[f] / (float)kN;
        float var = stats[64 + f] / (float)kN - mu * mu;
        mu_rstd[f] = mu;
        mu_rstd[64 + f] = rsqrtf(var + kEPS);
    }
}

// ---------------- SPADE fuse: y = leaky( BN(x) * (1 + amf@wg + bg) + amf@wb + bb ) ----
// Weights staged in LDS in 4 chunks of 32 k-rows: inner loop is pure LDS+FMA.

__global__ void k_spade(const float* __restrict__ xin, const float* __restrict__ amf,
                        const float* __restrict__ wg, const float* __restrict__ bg,
                        const float* __restrict__ wb, const float* __restrict__ bb,
                        const float* __restrict__ mu_rstd, float* __restrict__ y) {
    __shared__ float a[16 * 128];    // 8 KB amf tile
    __shared__ float wgs[32 * 64];   // 8 KB weight chunk (gamma)
    __shared__ float wbs[32 * 64];   // 8 KB weight chunk (beta)
    int tid = threadIdx.x;
    int n0 = blockIdx.x * 16;
    {   // stage amf tile via float4: 2048 floats = 512 float4, 2 per thread
        const float4* amf4 = (const float4*)amf;    // row = 32 float4
        float4* a4 = (float4*)a;
        #pragma unroll
        for (int i = 0; i < 2; ++i) {
            int idx = tid + 256 * i;
            int node = n0 + idx / 32;
            a4[idx] = (node < kN) ? amf4[(size_t)node * 32 + (idx & 31)]
                                  : make_float4(0.f, 0.f, 0.f, 0.f);
        }
    }
    int f = tid % 64, nl = tid / 64;
    float accg[4] = {0, 0, 0, 0}, accb[4] = {0, 0, 0, 0};
    const float4* wg4 = (const float4*)wg;   // [128][64] = 2048 float4; chunk = 512
    const float4* wb4 = (const float4*)wb;
    for (int c = 0; c < 4; ++c) {
        __syncthreads();   // c=0: a-tile visible; c>0: previous chunk fully consumed
        {
            float4* wgs4 = (float4*)wgs;
            float4* wbs4 = (float4*)wbs;
            #pragma unroll
            for (int i = 0; i < 2; ++i) {
                int idx = tid + 256 * i;
                wgs4[idx] = wg4[c * 512 + idx];
                wbs4[idx] = wb4[c * 512 + idx];
            }
        }
        __syncthreads();
        #pragma unroll
        for (int kk = 0; kk < 32; ++kk) {
            float wgk = wgs[kk * 64 + f], wbk = wbs[kk * 64 + f];
            int k = c * 32 + kk;
            #pragma unroll
            for (int j = 0; j < 4; ++j) {
                float av = a[(j * 4 + nl) * 128 + k];
                accg[j] += av * wgk;
                accb[j] += av * wbk;
            }
        }
    }
    float mu = mu_rstd[f], rstd = mu_rstd[64 + f];
    float bgf = bg[f], bbf = bb[f];
    #pragma unroll
    for (int j = 0; j < 4; ++j) {
        int node = n0 + j * 4 + nl;
        if (node < kN) {
            float xv = xin[(size_t)node * 64 + f];
            float g = accg[j] + bgf, b = accb[j] + bbf;
            float val = (xv - mu) * rstd * (1.f + g) + b;
            y[(size_t)node * 64 + f] = lrelu(val);
        }
    }
}

// ---------------- GAT: h = xin @ W ; es/ed per (node, head) ----------------
// W staged in LDS (16 KB) so the inner loop has NO global loads.

__global__ void k_gath(const float* __restrict__ xin, const float* __restrict__ W,
                       const float* __restrict__ as_, const float* __restrict__ ad_,
                       float* __restrict__ h, float* __restrict__ esed) {
    __shared__ float ws[64 * 64];  // 16 KB
    __shared__ float xs[16 * 64];  // 4 KB
    int tid = threadIdx.x;
    int n0 = blockIdx.x * 16;
    {   // stage W: 4096 floats = 1024 float4, 4 per thread
        const float4* W4 = (const float4*)W;
        float4* ws4 = (float4*)ws;
        #pragma unroll
        for (int i = 0; i < 4; ++i) ws4[tid + 256 * i] = W4[tid + 256 * i];
    }
    {   // stage x tile: 1024 floats = 256 float4, 1 per thread
        const float4* x4 = (const float4*)xin;      // row = 16 float4
        float4* xs4 = (float4*)xs;
        int node = n0 + tid / 16;
        xs4[tid] = (node < kN) ? x4[(size_t)node * 16 + (tid % 16)]
                               : make_float4(0.f, 0.f, 0.f, 0.f);
    }
    __syncthreads();
    int f = tid % 64, nl = tid / 64;
    float asf = as_[f], adf = ad_[f];
    float acc[4] = {0, 0, 0, 0};
    for (int k = 0; k < 64; ++k) {
        float w = ws[k * 64 + f];                    // LDS, lanes consecutive (2-way, free)
        #pragma unroll
        for (int j = 0; j < 4; ++j) acc[j] += xs[(j * 4 + nl) * 64 + k] * w;  // broadcast
    }
    #pragma unroll
    for (int j = 0; j < 4; ++j) {
        int node = n0 + j * 4 + nl;
        float hv = acc[j];
        float es = hv * asf, ed = hv * adf;
        #pragma unroll
        for (int off = 1; off < 16; off <<= 1) {
            es += __shfl_xor(es, off);
            ed += __shfl_xor(ed, off);
        }
        if (node < kN) {
            h[(size_t)node * 64 + f] = hv;
            if ((f & 15) == 0) {
                int hh = f >> 4;
                esed[node * 8 + hh] = es;
                esed[node * 8 + 4 + hh] = ed;
            }
        }
    }
}

// ---------------- GAT aggregate: ONLINE softmax over incoming edges (+self) ----------------

__global__ void k_gatagg(const float* __restrict__ h, const float* __restrict__ esed,
                         const int* __restrict__ rp, const int* __restrict__ col,
                         const float* __restrict__ bias, float* __restrict__ out) {
    int node = blockIdx.x * 4 + threadIdx.x / 64;
    if (node >= kN) return;
    int lane = threadIdx.x & 63;
    int hh = lane >> 4;
    float edv = esed[node * 8 + 4 + hh];
    float m = lrelu(esed[node * 8 + hh] + edv);   // self edge (p = 1 at current max)
    float d = 1.f;
    float acc = h[(size_t)node * 64 + lane];
    int b = rp[node], e2 = rp[node + 1];
    for (int i = b; i < e2; ++i) {
        int u = col[i];
        float e = lrelu(esed[u * 8 + hh] + edv);
        float hu = h[(size_t)u * 64 + lane];
        if (e <= m) {
            float p = __expf(e - m);
            d += p;
            acc += p * hu;
        } else {
            float s = __expf(m - e);
            d = d * s + 1.f;
            acc = acc * s + hu;
            m = e;
        }
    }
    out[(size_t)node * 64 + lane] = acc / d + bias[lane];
}

// ---------------- final add ----------------

__global__ void k_add(const float4* __restrict__ a, const float4* __restrict__ b,
                      float4* __restrict__ o, int n4) {
    int i = blockIdx.x * blockDim.x + threadIdx.x;
    if (i < n4) {
        float4 x = a[i], y = b[i];
        o[i] = make_float4(x.x + y.x, x.y + y.y, x.z + y.z, x.w + y.w);
    }
}

// ---------------- host ----------------

extern "C" void kernel_launch(void* const* d_in, const int* in_sizes, int n_in,
                              void* d_out, int out_size, void* d_ws, size_t ws_size,
                              hipStream_t stream) {
    const float* x    = (const float*)d_in[0];
    const float* mask = (const float*)d_in[1];
    const int*   ei   = (const int*)d_in[2];
    const float* s_w0[3] = {(const float*)d_in[3],  (const float*)d_in[9],  (const float*)d_in[15]};
    const float* s_b0[3] = {(const float*)d_in[4],  (const float*)d_in[10], (const float*)d_in[16]};
    const float* s_wg[3] = {(const float*)d_in[5],  (const float*)d_in[11], (const float*)d_in[17]};
    const float* s_bg[3] = {(const float*)d_in[6],  (const float*)d_in[12], (const float*)d_in[18]};
    const float* s_wb[3] = {(const float*)d_in[7],  (const float*)d_in[13], (const float*)d_in[19]};
    const float* s_bb[3] = {(const float*)d_in[8],  (const float*)d_in[14], (const float*)d_in[20]};
    const float* g_w[3]  = {(const float*)d_in[21], (const float*)d_in[25], (const float*)d_in[29]};
    const float* g_b[3]  = {(const float*)d_in[22], (const float*)d_in[26], (const float*)d_in[30]};
    const float* g_as[3] = {(const float*)d_in[23], (const float*)d_in[27], (const float*)d_in[31]};
    const float* g_ad[3] = {(const float*)d_in[24], (const float*)d_in[28], (const float*)d_in[32]};

    // workspace layout
    char* base = (char*)d_ws;
    size_t off = 0;
    auto alloc = [&](size_t bytes) -> void* {
        void* p = base + off;
        off = (off + bytes + 255) & ~(size_t)255;
        return p;
    };
    int*   cnt   = (int*)alloc((size_t)kN * 4);
    int*   rp    = (int*)alloc((size_t)(kN + 1) * 4);
    int*   fill  = (int*)alloc((size_t)kN * 4);
    int*   col   = (int*)alloc((size_t)kE * 4);
    float* dinv  = (float*)alloc((size_t)kN * 4);
    float* am    = (float*)alloc((size_t)kN * 16 * 4);
    float* P     = (float*)alloc((size_t)kN * 128 * 4);   // mf
    float* Q     = (float*)alloc((size_t)kN * 128 * 4);   // amf
    float* tY    = (float*)alloc((size_t)kN * 64 * 4);    // spade out
    float* tH    = (float*)alloc((size_t)kN * 64 * 4);    // gat h
    float* tZ    = (float*)alloc((size_t)kN * 64 * 4);    // z1 -> later zk
    float* tZ2   = (float*)alloc((size_t)kN * 64 * 4);    // z2
    float* esed  = (float*)alloc((size_t)kN * 8 * 4);
    float* sraw  = (float*)alloc(128 * 4);
    float* st_x  = (float*)alloc(128 * 4);                // mu/rstd of x
    float* st_z  = (float*)alloc(128 * 4);                // mu/rstd of z1
    (void)ws_size; (void)n_in; (void)in_sizes; (void)out_size;

    const int EB = (kE + 255) / 256;

    // graph build
    hipMemsetAsync(cnt, 0, (size_t)kN * 4, stream);
    hipMemsetAsync(fill, 0, (size_t)kN * 4, stream);
    k_count<<<EB, 256, 0, stream>>>(ei, cnt);
    k_scan<<<1, 1024, 0, stream>>>(cnt, rp, dinv);
    k_fill<<<EB, 256, 0, stream>>>(ei, rp, fill, col);

    // shared: am = A(mask), BN stats of x
    k_agg<16><<<(kN + 15) / 16, 256, 0, stream>>>(mask, am, dinv, rp, col);
    hipMemsetAsync(sraw, 0, 128 * 4, stream);
    k_bnstats<<<256, 256, 0, stream>>>(x, sraw);
    k_bnfin<<<1, 64, 0, stream>>>(sraw, st_x);

    const int GB16 = (kN + 15) / 16;   // 3125
    const int GB8  = (kN + 7) / 8;     // 6250 (k_agg128v)
    const int GB4  = (kN + 3) / 4;     // 12500

    // ---- s1 ----
    k_mf<<<GB16, 256, 0, stream>>>(am, s_w0[0], s_b0[0], P);
    k_agg128v<<<GB8, 256, 0, stream>>>(P, Q, dinv, rp, col);
    k_spade<<<GB16, 256, 0, stream>>>(x, Q, s_wg[0], s_bg[0], s_wb[0], s_bb[0], st_x, tY);
    // ---- g1 ----
    k_gath<<<GB16, 256, 0, stream>>>(tY, g_w[0], g_as[0], g_ad[0], tH, esed);
    k_gatagg<<<GB4, 256, 0, stream>>>(tH, esed, rp, col, g_b[0], tZ);

    // ---- s2 (BN over z1) ----
    hipMemsetAsync(sraw, 0, 128 * 4, stream);
    k_bnstats<<<256, 256, 0, stream>>>(tZ, sraw);
    k_bnfin<<<1, 64, 0, stream>>>(sraw, st_z);
    k_mf<<<GB16, 256, 0, stream>>>(am, s_w0[1], s_b0[1], P);
    k_agg128v<<<GB8, 256, 0, stream>>>(P, Q, dinv, rp, col);
    k_spade<<<GB16, 256, 0, stream>>>(tZ, Q, s_wg[1], s_bg[1], s_wb[1], s_bb[1], st_z, tY);
    // ---- g2 ----
    k_gath<<<GB16, 256, 0, stream>>>(tY, g_w[1], g_as[1], g_ad[1], tH, esed);
    k_gatagg<<<GB4, 256, 0, stream>>>(tH, esed, rp, col, g_b[1], tZ2);

    // ---- sk (BN over x, shared stats) ----
    k_mf<<<GB16, 256, 0, stream>>>(am, s_w0[2], s_b0[2], P);
    k_agg128v<<<GB8, 256, 0, stream>>>(P, Q, dinv, rp, col);
    k_spade<<<GB16, 256, 0, stream>>>(x, Q, s_wg[2], s_bg[2], s_wb[2], s_bb[2], st_x, tY);
    // ---- gk ----
    k_gath<<<GB16, 256, 0, stream>>>(tY, g_w[2], g_as[2], g_ad[2], tH, esed);
    k_gatagg<<<GB4, 256, 0, stream>>>(tH, esed, rp, col, g_b[2], tZ);  // z1 dead, reuse

    // out = z2 + zk
    k_add<<<(kN * 64 / 4 + 255) / 256, 256, 0, stream>>>((const float4*)tZ2, (const float4*)tZ,
                                                         (float4*)d_out, kN * 64 / 4);
}

// Round 9
// 1432.747 us; speedup vs baseline: 1.0712x; 1.0712x over previous
//
#include <hip/hip_runtime.h>
#include <hip/hip_bf16.h>

// Problem constants (fixed by the reference)
constexpr int kN   = 50000;
constexpr int kE   = 800000;
constexpr int kIN  = 64;
constexpr int kMC  = 16;
constexpr int kH   = 4;
constexpr int kC   = 16;
constexpr int kHID = 128;
constexpr float kNEG = 0.2f;
constexpr float kEPS = 1e-5f;

__device__ __forceinline__ float lrelu(float x) { return x > 0.f ? x : kNEG * x; }

// ---------------- graph build ----------------

__global__ void k_count(const int* __restrict__ ei, int* __restrict__ cnt) {
    int e = blockIdx.x * blockDim.x + threadIdx.x;
    if (e < kE) atomicAdd(&cnt[ei[kE + e]], 1);   // dst = ei[1][e]
}

// single block, 1024 threads: exclusive scan of cnt -> rp, also dinv = rsqrt(cnt+1)
__global__ void k_scan(const int* __restrict__ cnt, int* __restrict__ rp,
                       float* __restrict__ dinv) {
    __shared__ int wsum[16];
    __shared__ int chunk_base;
    int tid = threadIdx.x, lane = tid & 63, wid = tid >> 6;
    if (tid == 0) chunk_base = 0;
    __syncthreads();
    for (int base = 0; base < kN; base += 1024) {
        int i = base + tid;
        int v = (i < kN) ? cnt[i] : 0;
        if (i < kN) dinv[i] = rsqrtf((float)(v + 1));
        // wave inclusive scan
        int s = v;
        #pragma unroll
        for (int off = 1; off < 64; off <<= 1) {
            int t = __shfl_up(s, off);
            if (lane >= off) s += t;
        }
        if (lane == 63) wsum[wid] = s;
        __syncthreads();
        if (wid == 0) {
            int t = (lane < 16) ? wsum[lane] : 0;
            #pragma unroll
            for (int off = 1; off < 16; off <<= 1) {
                int u = __shfl_up(t, off);
                if (lane >= off) t += u;
            }
            if (lane < 16) wsum[lane] = t;
        }
        __syncthreads();
        int wbase = (wid > 0) ? wsum[wid - 1] : 0;
        int total = wsum[15];
        int excl = chunk_base + wbase + s - v;
        if (i < kN) rp[i] = excl;
        __syncthreads();
        if (tid == 0) chunk_base += total;
        __syncthreads();
    }
    if (threadIdx.x == 0) rp[kN] = chunk_base;
}

__global__ void k_fill(const int* __restrict__ ei, const int* __restrict__ rp,
                       int* __restrict__ fill, int* __restrict__ col) {
    int e = blockIdx.x * blockDim.x + threadIdx.x;
    if (e < kE) {
        int d = ei[kE + e];
        int pos = rp[d] + atomicAdd(&fill[d], 1);
        col[pos] = ei[e];
    }
}

// ---------------- normalized aggregation (scalar, for F=16): ----
// out[v] = dinv[v]*(dinv[v]*in[v] + sum_u dinv[u]*in[u])

template <int F>
__global__ void k_agg(const float* __restrict__ in, float* __restrict__ out,
                      const float* __restrict__ dinv, const int* __restrict__ rp,
                      const int* __restrict__ col) {
    constexpr int NPB = 256 / F;
    int node = blockIdx.x * NPB + threadIdx.x / F;
    int f = threadIdx.x % F;
    if (node >= kN) return;
    float dv = dinv[node];
    float acc = dv * in[(size_t)node * F + f];     // self loop term (dinv[v]^2 * in[v]) /dv
    int b = rp[node], e2 = rp[node + 1];
    for (int i = b; i < e2; ++i) {
        int u = col[i];
        acc += dinv[u] * in[(size_t)u * F + f];
    }
    out[(size_t)node * F + f] = dv * acc;
}

// ---- aggregation for F=128 over PRE-SCALED input (Ps = dinv .* mf):
// out[v] = dinv[v] * (Ps[v] + sum_u Ps[u]).
// Chunked col loads: 32 lanes cooperatively fetch 32 indices (coalesced), then
// broadcast via shfl -> row loads are independent (deep MLP, no load->load chain).

__global__ void k_agg128v(const float* __restrict__ in, float* __restrict__ out,
                          const float* __restrict__ dinv, const int* __restrict__ rp,
                          const int* __restrict__ col) {
    int node = blockIdx.x * 8 + threadIdx.x / 32;   // 8 nodes per 256-thread block
    int l = threadIdx.x & 31;                       // float4 col index
    if (node >= kN) return;
    const float4* in4 = (const float4*)in;
    float dv = dinv[node];
    float4 acc = in4[(size_t)node * 32 + l];        // self term Ps[v]
    int b = rp[node], e2 = rp[node + 1];
    for (int base = b; base < e2; base += 32) {
        int idx = base + l;
        int myu = (idx < e2) ? col[idx] : 0;        // coalesced chunk of indices
        int n = min(32, e2 - base);
        for (int cc = 0; cc < n; ++cc) {
            int u = __shfl(myu, cc, 32);            // uniform broadcast (register)
            float4 w = in4[(size_t)u * 32 + l];     // independent row load
            acc.x += w.x; acc.y += w.y; acc.z += w.z; acc.w += w.w;
        }
    }
    ((float4*)out)[(size_t)node * 32 + l] =
        make_float4(dv * acc.x, dv * acc.y, dv * acc.z, dv * acc.w);
}

// ---------------- Ps = dinv .* relu(am @ w0 + b0), am: N x 16, w0: 16 x 128 ----------------

__global__ void k_mf(const float* __restrict__ am, const float* __restrict__ w0,
                     const float* __restrict__ b0, const float* __restrict__ dinv,
                     float* __restrict__ mf) {
    __shared__ float w[16 * 128];
    __shared__ float a[16 * 16];
    int tid = threadIdx.x;
    int n0 = blockIdx.x * 16;
    {   // stage w0: 2048 floats = 512 float4, 2 per thread
        const float4* w04 = (const float4*)w0;
        float4* w4 = (float4*)w;
        #pragma unroll
        for (int i = 0; i < 2; ++i) w4[tid + 256 * i] = w04[tid + 256 * i];
        // stage am tile: 256 floats = 64 float4
        if (tid < 64) {
            const float4* am4 = (const float4*)am;   // row = 4 float4
            int node = n0 + tid / 4;
            ((float4*)a)[tid] = (node < kN) ? am4[(size_t)node * 4 + (tid & 3)]
                                            : make_float4(0.f, 0.f, 0.f, 0.f);
        }
    }
    __syncthreads();
    int f = tid % 128, g = tid / 128;   // g in {0,1}
    float bf = b0[f];
    for (int j = 0; j < 8; ++j) {
        int nl = g * 8 + j;
        int node = n0 + nl;
        if (node < kN) {
            float acc = bf;
            #pragma unroll
            for (int k = 0; k < 16; ++k) acc += a[nl * 16 + k] * w[k * 128 + f];
            mf[(size_t)node * 128 + f] = dinv[node] * fmaxf(acc, 0.f);
        }
    }
}

// ---------------- BatchNorm stats (biased var) over N rows of 64 cols ----------------

__global__ void k_bnstats(const float* __restrict__ x, float* __restrict__ stats) {
    int f = threadIdx.x % 64, r0 = threadIdx.x / 64;  // 4 row groups
    float s = 0.f, s2 = 0.f;
    for (int v = blockIdx.x * 4 + r0; v < kN; v += gridDim.x * 4) {
        float val = x[(size_t)v * 64 + f];
        s += val; s2 += val * val;
    }
    __shared__ float sh[256], sh2[256];
    sh[threadIdx.x] = s; sh2[threadIdx.x] = s2;
    __syncthreads();
    if (threadIdx.x < 64) {
        s  = sh[threadIdx.x]  + sh[threadIdx.x + 64]  + sh[threadIdx.x + 128]  + sh[threadIdx.x + 192];
        s2 = sh2[threadIdx.x] + sh2[threadIdx.x + 64] + sh2[threadIdx.x + 128] + sh2[threadIdx.x + 192];
        atomicAdd(&stats[f], s);
        atomicAdd(&stats[64 + f], s2);
    }
}

__global__ void k_bnfin(const float* __restrict__ stats, float* __restrict__ mu_rstd) {
    int f = threadIdx.x;
    if (f < 64) {
        float mu = stats[f] / (float)kN;
        float var = stats[64 + f] / (float)kN - mu * mu;
        mu_rstd[f] = mu;
        mu_rstd[64 + f] = rsqrtf(var + kEPS);
    }
}

// ---------------- SPADE fuse: y = leaky( BN(x) * (1 + amf@wg + bg) + amf@wb + bb ) ----
// Weights staged in LDS in 4 chunks of 32 k-rows: inner loop is pure LDS+FMA.

__global__ void k_spade(const float* __restrict__ xin, const float* __restrict__ amf,
                        const float* __restrict__ wg, const float* __restrict__ bg,
                        const float* __restrict__ wb, const float* __restrict__ bb,
                        const float* __restrict__ mu_rstd, float* __restrict__ y) {
    __shared__ float a[16 * 128];    // 8 KB amf tile
    __shared__ float wgs[32 * 64];   // 8 KB weight chunk (gamma)
    __shared__ float wbs[32 * 64];   // 8 KB weight chunk (beta)
    int tid = threadIdx.x;
    int n0 = blockIdx.x * 16;
    {   // stage amf tile via float4: 2048 floats = 512 float4, 2 per thread
        const float4* amf4 = (const float4*)amf;    // row = 32 float4
        float4* a4 = (float4*)a;
        #pragma unroll
        for (int i = 0; i < 2; ++i) {
            int idx = tid + 256 * i;
            int node = n0 + idx / 32;
            a4[idx] = (node < kN) ? amf4[(size_t)node * 32 + (idx & 31)]
                                  : make_float4(0.f, 0.f, 0.f, 0.f);
        }
    }
    int f = tid % 64, nl = tid / 64;
    float accg[4] = {0, 0, 0, 0}, accb[4] = {0, 0, 0, 0};
    const float4* wg4 = (const float4*)wg;   // [128][64] = 2048 float4; chunk = 512
    const float4* wb4 = (const float4*)wb;
    for (int c = 0; c < 4; ++c) {
        __syncthreads();   // c=0: a-tile visible; c>0: previous chunk fully consumed
        {
            float4* wgs4 = (float4*)wgs;
            float4* wbs4 = (float4*)wbs;
            #pragma unroll
            for (int i = 0; i < 2; ++i) {
                int idx = tid + 256 * i;
                wgs4[idx] = wg4[c * 512 + idx];
                wbs4[idx] = wb4[c * 512 + idx];
            }
        }
        __syncthreads();
        #pragma unroll
        for (int kk = 0; kk < 32; ++kk) {
            float wgk = wgs[kk * 64 + f], wbk = wbs[kk * 64 + f];
            int k = c * 32 + kk;
            #pragma unroll
            for (int j = 0; j < 4; ++j) {
                float av = a[(j * 4 + nl) * 128 + k];
                accg[j] += av * wgk;
                accb[j] += av * wbk;
            }
        }
    }
    float mu = mu_rstd[f], rstd = mu_rstd[64 + f];
    float bgf = bg[f], bbf = bb[f];
    #pragma unroll
    for (int j = 0; j < 4; ++j) {
        int node = n0 + j * 4 + nl;
        if (node < kN) {
            float xv = xin[(size_t)node * 64 + f];
            float g = accg[j] + bgf, b = accb[j] + bbf;
            float val = (xv - mu) * rstd * (1.f + g) + b;
            y[(size_t)node * 64 + f] = lrelu(val);
        }
    }
}

// ---------------- GAT: h = xin @ W ; es/ed per (node, head) ----------------
// UNCHANGED from R8 (control for the attribution experiment).

__global__ void k_gath(const float* __restrict__ xin, const float* __restrict__ W,
                       const float* __restrict__ as_, const float* __restrict__ ad_,
                       float* __restrict__ h, float* __restrict__ esed) {
    __shared__ float ws[64 * 64];  // 16 KB
    __shared__ float xs[16 * 64];  // 4 KB
    int tid = threadIdx.x;
    int n0 = blockIdx.x * 16;
    {   // stage W: 4096 floats = 1024 float4, 4 per thread
        const float4* W4 = (const float4*)W;
        float4* ws4 = (float4*)ws;
        #pragma unroll
        for (int i = 0; i < 4; ++i) ws4[tid + 256 * i] = W4[tid + 256 * i];
    }
    {   // stage x tile: 1024 floats = 256 float4, 1 per thread
        const float4* x4 = (const float4*)xin;      // row = 16 float4
        float4* xs4 = (float4*)xs;
        int node = n0 + tid / 16;
        xs4[tid] = (node < kN) ? x4[(size_t)node * 16 + (tid % 16)]
                               : make_float4(0.f, 0.f, 0.f, 0.f);
    }
    __syncthreads();
    int f = tid % 64, nl = tid / 64;
    float asf = as_[f], adf = ad_[f];
    float acc[4] = {0, 0, 0, 0};
    for (int k = 0; k < 64; ++k) {
        float w = ws[k * 64 + f];                    // LDS, lanes consecutive (2-way, free)
        #pragma unroll
        for (int j = 0; j < 4; ++j) acc[j] += xs[(j * 4 + nl) * 64 + k] * w;  // broadcast
    }
    #pragma unroll
    for (int j = 0; j < 4; ++j) {
        int node = n0 + j * 4 + nl;
        float hv = acc[j];
        float es = hv * asf, ed = hv * adf;
        #pragma unroll
        for (int off = 1; off < 16; off <<= 1) {
            es += __shfl_xor(es, off);
            ed += __shfl_xor(ed, off);
        }
        if (node < kN) {
            h[(size_t)node * 64 + f] = hv;
            if ((f & 15) == 0) {
                int hh = f >> 4;
                esed[node * 8 + hh] = es;
                esed[node * 8 + 4 + hh] = ed;
            }
        }
    }
}

// ---------------- GAT aggregate: ONLINE softmax, chunked col loads ----------------

__global__ void k_gatagg(const float* __restrict__ h, const float* __restrict__ esed,
                         const int* __restrict__ rp, const int* __restrict__ col,
                         const float* __restrict__ bias, float* __restrict__ out) {
    int node = blockIdx.x * 4 + threadIdx.x / 64;
    if (node >= kN) return;
    int lane = threadIdx.x & 63;
    int hh = lane >> 4;
    float edv = esed[node * 8 + 4 + hh];
    float m = lrelu(esed[node * 8 + hh] + edv);   // self edge (p = 1 at current max)
    float d = 1.f;
    float acc = h[(size_t)node * 64 + lane];
    int b = rp[node], e2 = rp[node + 1];
    for (int base = b; base < e2; base += 64) {
        int idx = base + lane;
        int myu = (idx < e2) ? col[idx] : 0;       // coalesced chunk of indices
        int n = min(64, e2 - base);
        for (int cc = 0; cc < n; ++cc) {
            int u = __shfl(myu, cc);               // register broadcast
            float e = lrelu(esed[u * 8 + hh] + edv);
            float hu = h[(size_t)u * 64 + lane];   // independent coalesced row
            if (e <= m) {
                float p = __expf(e - m);
                d += p;
                acc += p * hu;
            } else {
                float s = __expf(m - e);
                d = d * s + 1.f;
                acc = acc * s + hu;
                m = e;
            }
        }
    }
    out[(size_t)node * 64 + lane] = acc / d + bias[lane];
}

// ---------------- final add ----------------

__global__ void k_add(const float4* __restrict__ a, const float4* __restrict__ b,
                      float4* __restrict__ o, int n4) {
    int i = blockIdx.x * blockDim.x + threadIdx.x;
    if (i < n4) {
        float4 x = a[i], y = b[i];
        o[i] = make_float4(x.x + y.x, x.y + y.y, x.z + y.z, x.w + y.w);
    }
}

// ---------------- host ----------------

extern "C" void kernel_launch(void* const* d_in, const int* in_sizes, int n_in,
                              void* d_out, int out_size, void* d_ws, size_t ws_size,
                              hipStream_t stream) {
    const float* x    = (const float*)d_in[0];
    const float* mask = (const float*)d_in[1];
    const int*   ei   = (const int*)d_in[2];
    const float* s_w0[3] = {(const float*)d_in[3],  (const float*)d_in[9],  (const float*)d_in[15]};
    const float* s_b0[3] = {(const float*)d_in[4],  (const float*)d_in[10], (const float*)d_in[16]};
    const float* s_wg[3] = {(const float*)d_in[5],  (const float*)d_in[11], (const float*)d_in[17]};
    const float* s_bg[3] = {(const float*)d_in[6],  (const float*)d_in[12], (const float*)d_in[18]};
    const float* s_wb[3] = {(const float*)d_in[7],  (const float*)d_in[13], (const float*)d_in[19]};
    const float* s_bb[3] = {(const float*)d_in[8],  (const float*)d_in[14], (const float*)d_in[20]};
    const float* g_w[3]  = {(const float*)d_in[21], (const float*)d_in[25], (const float*)d_in[29]};
    const float* g_b[3]  = {(const float*)d_in[22], (const float*)d_in[26], (const float*)d_in[30]};
    const float* g_as[3] = {(const float*)d_in[23], (const float*)d_in[27], (const float*)d_in[31]};
    const float* g_ad[3] = {(const float*)d_in[24], (const float*)d_in[28], (const float*)d_in[32]};

    // workspace layout
    char* base = (char*)d_ws;
    size_t off = 0;
    auto alloc = [&](size_t bytes) -> void* {
        void* p = base + off;
        off = (off + bytes + 255) & ~(size_t)255;
        return p;
    };
    int*   cnt   = (int*)alloc((size_t)kN * 4);
    int*   rp    = (int*)alloc((size_t)(kN + 1) * 4);
    int*   fill  = (int*)alloc((size_t)kN * 4);
    int*   col   = (int*)alloc((size_t)kE * 4);
    float* dinv  = (float*)alloc((size_t)kN * 4);
    float* am    = (float*)alloc((size_t)kN * 16 * 4);
    float* P     = (float*)alloc((size_t)kN * 128 * 4);   // Ps (dinv-scaled mf)
    float* Q     = (float*)alloc((size_t)kN * 128 * 4);   // amf
    float* tY    = (float*)alloc((size_t)kN * 64 * 4);    // spade out
    float* tH    = (float*)alloc((size_t)kN * 64 * 4);    // gat h
    float* tZ    = (float*)alloc((size_t)kN * 64 * 4);    // z1 -> later zk
    float* tZ2   = (float*)alloc((size_t)kN * 64 * 4);    // z2
    float* esed  = (float*)alloc((size_t)kN * 8 * 4);
    float* sraw  = (float*)alloc(128 * 4);
    float* st_x  = (float*)alloc(128 * 4);                // mu/rstd of x
    float* st_z  = (float*)alloc(128 * 4);                // mu/rstd of z1
    (void)ws_size; (void)n_in; (void)in_sizes; (void)out_size;

    const int EB = (kE + 255) / 256;

    // graph build
    hipMemsetAsync(cnt, 0, (size_t)kN * 4, stream);
    hipMemsetAsync(fill, 0, (size_t)kN * 4, stream);
    k_count<<<EB, 256, 0, stream>>>(ei, cnt);
    k_scan<<<1, 1024, 0, stream>>>(cnt, rp, dinv);
    k_fill<<<EB, 256, 0, stream>>>(ei, rp, fill, col);

    // shared: am = A(mask), BN stats of x
    k_agg<16><<<(kN + 15) / 16, 256, 0, stream>>>(mask, am, dinv, rp, col);
    hipMemsetAsync(sraw, 0, 128 * 4, stream);
    k_bnstats<<<256, 256, 0, stream>>>(x, sraw);
    k_bnfin<<<1, 64, 0, stream>>>(sraw, st_x);

    const int GB16 = (kN + 15) / 16;   // 3125
    const int GB8  = (kN + 7) / 8;     // 6250 (k_agg128v)
    const int GB4  = (kN + 3) / 4;     // 12500

    // ---- s1 ----
    k_mf<<<GB16, 256, 0, stream>>>(am, s_w0[0], s_b0[0], dinv, P);
    k_agg128v<<<GB8, 256, 0, stream>>>(P, Q, dinv, rp, col);
    k_spade<<<GB16, 256, 0, stream>>>(x, Q, s_wg[0], s_bg[0], s_wb[0], s_bb[0], st_x, tY);
    // ---- g1 ----
    k_gath<<<GB16, 256, 0, stream>>>(tY, g_w[0], g_as[0], g_ad[0], tH, esed);
    k_gatagg<<<GB4, 256, 0, stream>>>(tH, esed, rp, col, g_b[0], tZ);

    // ---- s2 (BN over z1) ----
    hipMemsetAsync(sraw, 0, 128 * 4, stream);
    k_bnstats<<<256, 256, 0, stream>>>(tZ, sraw);
    k_bnfin<<<1, 64, 0, stream>>>(sraw, st_z);
    k_mf<<<GB16, 256, 0, stream>>>(am, s_w0[1], s_b0[1], dinv, P);
    k_agg128v<<<GB8, 256, 0, stream>>>(P, Q, dinv, rp, col);
    k_spade<<<GB16, 256, 0, stream>>>(tZ, Q, s_wg[1], s_bg[1], s_wb[1], s_bb[1], st_z, tY);
    // ---- g2 ----
    k_gath<<<GB16, 256, 0, stream>>>(tY, g_w[1], g_as[1], g_ad[1], tH, esed);
    k_gatagg<<<GB4, 256, 0, stream>>>(tH, esed, rp, col, g_b[1], tZ2);

    // ---- sk (BN over x, shared stats) ----
    k_mf<<<GB16, 256, 0, stream>>>(am, s_w0[2], s_b0[2], dinv, P);
    k_agg128v<<<GB8, 256, 0, stream>>>(P, Q, dinv, rp, col);
    k_spade<<<GB16, 256, 0, stream>>>(x, Q, s_wg[2], s_bg[2], s_wb[2], s_bb[2], st_x, tY);
    // ---- gk ----
    k_gath<<<GB16, 256, 0, stream>>>(tY, g_w[2], g_as[2], g_ad[2], tH, esed);
    k_gatagg<<<GB4, 256, 0, stream>>>(tH, esed, rp, col, g_b[2], tZ);  // z1 dead, reuse

    // out = z2 + zk
    k_add<<<(kN * 64 / 4 + 255) / 256, 256, 0, stream>>>((const float4*)tZ2, (const float4*)tZ,
                                                         (float4*)d_out, kN * 64 / 4);
}